// Round 15
// baseline (414.369 us; speedup 1.0000x reference)
//
#include <hip/hip_runtime.h>
#include <math.h>

#define BK_SHIFT 7            // 128 nodes per bucket
#define BK_NODES 128
#define BK_CAP   4608         // slack bucket capacity: mean 4096 + 8 sigma

typedef _Float16 h2 __attribute__((ext_vector_type(2)));
typedef _Float16 f16x8 __attribute__((ext_vector_type(8)));
typedef float f32x4 __attribute__((ext_vector_type(4)));

__device__ __forceinline__ h2 u2h(unsigned u){ return __builtin_bit_cast(h2, u); }

__device__ __forceinline__ int dev_lower_bound(const int* __restrict__ a, int n, int v){
  int lo = 0, hi = n;
  while (lo < hi){ int mid = (lo + hi) >> 1; if (a[mid] < v) lo = mid + 1; else hi = mid; }
  return lo;
}

// ================= one-pass partition (+W-prep on blocks 0..47) =============
__global__ __launch_bounds__(256) void p3_prep_kernel(
    const int* __restrict__ esrc, const int* __restrict__ edst,
    int* __restrict__ bktCnt, unsigned* __restrict__ ebuf, int nE, int K,
    const float* __restrict__ W0, const float* __restrict__ W1,
    const float* __restrict__ W2, const float* __restrict__ W3,
    const float* __restrict__ W4m, const float* __restrict__ W5m,
    unsigned short* __restrict__ Wt16)
{
  __shared__ int cnt[512];
  __shared__ int base[512];
  if (blockIdx.x < 48){
    const float* Ws[6] = {W0, W1, W2, W3, W4m, W5m};
    const int mat = blockIdx.x >> 3;
    const int chunk = blockIdx.x & 7;
    const float* W = Ws[mat];
    unsigned short* o = Wt16 + mat * 16384;
    #pragma unroll
    for (int e = 0; e < 8; ++e){
      int i = chunk * 2048 + e * 256 + threadIdx.x;
      int k = i >> 7, col = i & 127;
      _Float16 h = (_Float16)W[i];
      o[col * 128 + k] = __builtin_bit_cast(unsigned short, h);
    }
    return;
  }
  const int bx = blockIdx.x - 48;
  const int t = threadIdx.x;
  for (int k = t; k < K; k += 256) cnt[k] = 0;
  __syncthreads();
  const int i0 = (bx * 256 + t) * 8;
  const int i1 = min(i0 + 8, nE);
  const int cl = (i0 < nE) ? (i1 - i0) : 0;
  int bkt[8];
  unsigned pk[8];
  for (int j = 0; j < cl; ++j){
    int sv = esrc[i0 + j];
    int dv = edst[i0 + j];
    bkt[j] = dv >> BK_SHIFT;
    pk[j] = ((unsigned)sv << BK_SHIFT) | (unsigned)(dv & (BK_NODES - 1));
    atomicAdd(&cnt[bkt[j]], 1);
  }
  __syncthreads();
  for (int k = t; k < K; k += 256){
    int c = cnt[k];
    base[k] = c ? atomicAdd(&bktCnt[k], c) : 0;   // global chunk reservation
  }
  __syncthreads();
  for (int k = t; k < K; k += 256) cnt[k] = 0;
  __syncthreads();
  for (int j = 0; j < cl; ++j){
    int r = atomicAdd(&cnt[bkt[j]], 1);
    ebuf[(size_t)bkt[j] * BK_CAP + base[bkt[j]] + r] = pk[j];
  }
}

// P4: per-bucket CSR build; e0 derived from actual bucket counts.
// Degree histogram (LPT-reversed bins) folded in. row_off[n] from block 0.
__global__ __launch_bounds__(256) void p4_build(const unsigned* __restrict__ ebuf,
    const int* __restrict__ bktCnt, int* __restrict__ row_off,
    int* __restrict__ csr_src, int* __restrict__ dbins, int n, int nE){
  const int b = blockIdx.x;
  const int node0 = b << BK_SHIFT;
  const int nNodes = min(BK_NODES, n - node0);
  const int tid = threadIdx.x;
  __shared__ int ldeg[BK_NODES];
  __shared__ int lcur[BK_NODES];
  __shared__ int sc[BK_NODES];
  __shared__ int dh[256];
  __shared__ int red[256];
  if (b == 0 && tid == 0) row_off[n] = nE + n;
  int partial = 0;
  for (int k = tid; k < b; k += 256) partial += bktCnt[k];
  red[tid] = partial;
  __syncthreads();
  for (int off = 128; off > 0; off >>= 1){
    if (tid < off) red[tid] += red[tid + off];
    __syncthreads();
  }
  const int e0 = red[0];
  const int ecnt = bktCnt[b];
  const unsigned* eb = ebuf + (size_t)b * BK_CAP;
  __syncthreads();
  if (tid < BK_NODES) ldeg[tid] = 0;
  dh[tid] = 0;
  __syncthreads();
  for (int i = tid; i < ecnt; i += 256)
    atomicAdd(&ldeg[eb[i] & (BK_NODES - 1)], 1);
  __syncthreads();
  if (tid < BK_NODES) sc[tid] = (tid < nNodes) ? (ldeg[tid] + 1) : 0;
  __syncthreads();
  for (int off = 1; off < BK_NODES; off <<= 1){
    int u = 0;
    if (tid < BK_NODES && tid >= off) u = sc[tid - off];
    __syncthreads();
    if (tid < BK_NODES) sc[tid] += u;
    __syncthreads();
  }
  if (tid < nNodes){
    const int csr0 = e0 + node0;
    int ro = csr0 + sc[tid] - (ldeg[tid] + 1);
    row_off[node0 + tid] = ro;
    lcur[tid] = ro;
    atomicAdd(&dh[255 - min(ldeg[tid] + 1, 255)], 1);   // LPT bins
  }
  __syncthreads();
  for (int i = tid; i < ecnt; i += 256){
    unsigned e = eb[i];
    int p = atomicAdd(&lcur[e & (BK_NODES - 1)], 1);
    csr_src[p] = (int)(e >> BK_SHIFT);
  }
  __syncthreads();
  if (tid < nNodes)
    csr_src[lcur[tid]] = node0 + tid;                   // self-loop at row end
  if (dh[tid]) atomicAdd(&dbins[tid], dh[tid]);
}

// ================= degree order (LPT): fused scan + scatter =================
// Each block computes the 256-bin exclusive scan locally from dbins, then
// reserves per-bin chunks via zero-based dres cursors.
__global__ __launch_bounds__(256) void deg_scatter(const int* __restrict__ row_off,
    const int* __restrict__ dbins, int* __restrict__ dres,
    int* __restrict__ order, int n){
  __shared__ int sh[256];
  __shared__ int cnt[256];
  __shared__ int base[256];
  const int t = threadIdx.x;
  const int v = dbins[t];
  sh[t] = v;
  cnt[t] = 0;
  __syncthreads();
  for (int off = 1; off < 256; off <<= 1){
    int u = (t >= off) ? sh[t - off] : 0;
    __syncthreads();
    sh[t] += u;
    __syncthreads();
  }
  const int gbase = sh[t] - v;       // exclusive global bin base
  __syncthreads();
  int i = blockIdx.x * 256 + t;
  int bin = 0, r = 0;
  if (i < n){
    int deg = row_off[i + 1] - row_off[i];
    bin = 255 - min(deg, 255);       // LPT: high degree first
    r = atomicAdd(&cnt[bin], 1);
  }
  __syncthreads();
  base[t] = cnt[t] ? (gbase + atomicAdd(&dres[t], cnt[t])) : 0;
  __syncthreads();
  if (i < n) order[base[bin] + r] = i;
}

// ---------------- MFMA GEMM: xl/xr = f16(X) @ {Wl,Wr} + b ------------------
template<bool F16IN>
__global__ __launch_bounds__(256) void gemm_mfma_kernel(
    const void* __restrict__ Xv,
    const unsigned short* __restrict__ WtL,   // [2][128col][128k] f16
    const float* __restrict__ bl, const float* __restrict__ br,
    unsigned short* __restrict__ xl16, unsigned short* __restrict__ xr16, int n)
{
  const int w   = threadIdx.x >> 6;
  const int l   = threadIdx.x & 63;
  const int l15 = l & 15;
  const int kq  = l >> 4;
  const int row = blockIdx.x * 64 + w * 16 + l15;
  const bool ok = row < n;
  const int rc = min(row, n - 1);

  f16x8 a[4];
  #pragma unroll
  for (int ks = 0; ks < 4; ++ks){
    if (F16IN){
      const unsigned short* src = (const unsigned short*)Xv + (size_t)rc * 128 + kq * 8 + ks * 32;
      a[ks] = ok ? *(const f16x8*)src : (f16x8){0,0,0,0,0,0,0,0};
    } else {
      const float* src = (const float*)Xv + (size_t)rc * 128 + kq * 8 + ks * 32;
      float4 f0 = ok ? *(const float4*)(src)     : make_float4(0.f,0.f,0.f,0.f);
      float4 f1 = ok ? *(const float4*)(src + 4) : make_float4(0.f,0.f,0.f,0.f);
      f16x8 v;
      v[0] = (_Float16)f0.x; v[1] = (_Float16)f0.y;
      v[2] = (_Float16)f0.z; v[3] = (_Float16)f0.w;
      v[4] = (_Float16)f1.x; v[5] = (_Float16)f1.y;
      v[6] = (_Float16)f1.z; v[7] = (_Float16)f1.w;
      a[ks] = v;
    }
  }

  const int rowblk = blockIdx.x * 64 + w * 16;
  #pragma unroll
  for (int mat = 0; mat < 2; ++mat){
    const unsigned short* Wt = WtL + mat * 16384;
    const float* bias = mat ? br : bl;
    unsigned short* out = mat ? xr16 : xl16;
    f32x4 acc[8];
    #pragma unroll
    for (int ct = 0; ct < 8; ++ct) acc[ct] = (f32x4){0.f, 0.f, 0.f, 0.f};
    #pragma unroll
    for (int ks = 0; ks < 4; ++ks){
      #pragma unroll
      for (int ct = 0; ct < 8; ++ct){
        f16x8 b = *(const f16x8*)(Wt + (size_t)(ct * 16 + l15) * 128 + ks * 32 + kq * 8);
        acc[ct] = __builtin_amdgcn_mfma_f32_16x16x32_f16(a[ks], b, acc[ct], 0, 0, 0);
      }
    }
    #pragma unroll
    for (int ct = 0; ct < 8; ++ct){
      const float bv = bias[ct * 16 + l15];
      #pragma unroll
      for (int rg = 0; rg < 4; ++rg){
        const int r = rowblk + kq * 4 + rg;
        if (r < n){
          _Float16 h = (_Float16)(acc[ct][rg] + bv);
          out[(size_t)r * 128 + ct * 16 + l15] = __builtin_bit_cast(unsigned short, h);
        }
      }
    }
  }
}

// ---------------- per-destination online-softmax attention ----------------
__global__ __launch_bounds__(256) void edge_attn_kernel(
    const unsigned short* __restrict__ xl16, const unsigned short* __restrict__ xr16,
    const int* __restrict__ row_off, const int* __restrict__ csr_src,
    const int* __restrict__ order,
    const float* __restrict__ att, const float* __restrict__ bias,
    unsigned short* __restrict__ out16, int n, int do_relu)
{
  const int gid = (blockIdx.x * blockDim.x + threadIdx.x) >> 4;
  const int node = order[min(gid, n - 1)];
  const int lane16 = threadIdx.x & 15;
  const int f8 = lane16 * 8;

  const uint4 xru = *(const uint4*)(xr16 + (size_t)node * 128 + f8);
  const h2 xr0 = u2h(xru.x), xr1 = u2h(xru.y), xr2 = u2h(xru.z), xr3 = u2h(xru.w);
  const float4 aA = *(const float4*)(att + f8);
  const float4 aB = *(const float4*)(att + f8 + 4);
  const h2 at0 = {(_Float16)aA.x, (_Float16)aA.y};
  const h2 at1 = {(_Float16)aA.z, (_Float16)aA.w};
  const h2 at2 = {(_Float16)aB.x, (_Float16)aB.y};
  const h2 at3 = {(_Float16)aB.z, (_Float16)aB.w};
  const h2 k02 = {(_Float16)0.2f, (_Float16)0.2f};

  const int base = row_off[node];
  const int deg  = row_off[node + 1] - base;
  int dmax = max(deg, __shfl_xor(deg, 16));
  dmax = max(dmax, __shfl_xor(dmax, 32));

  auto part = [&](uint4 xp) -> float {
    h2 u0 = u2h(xp.x) + xr0;
    h2 u1 = u2h(xp.y) + xr1;
    h2 u2 = u2h(xp.z) + xr2;
    h2 u3 = u2h(xp.w) + xr3;
    u0 = __builtin_elementwise_max(u0, u0 * k02);
    u1 = __builtin_elementwise_max(u1, u1 * k02);
    u2 = __builtin_elementwise_max(u2, u2 * k02);
    u3 = __builtin_elementwise_max(u3, u3 * k02);
    float ps = __builtin_amdgcn_fdot2(u0, at0, 0.f, false);
    ps = __builtin_amdgcn_fdot2(u1, at1, ps, false);
    ps = __builtin_amdgcn_fdot2(u2, at2, ps, false);
    ps = __builtin_amdgcn_fdot2(u3, at3, ps, false);
    return ps;
  };

  uint4 xp = *(const uint4*)(xl16 + (size_t)csr_src[base] * 128 + f8);
  float p = part(xp);
  p += __shfl_xor(p, 1); p += __shfl_xor(p, 2);
  p += __shfl_xor(p, 4); p += __shfl_xor(p, 8);
  float m = p, Mrun = p, s = 1.f;
  h2 A0 = u2h(xp.x), A1 = u2h(xp.y), A2 = u2h(xp.z), A3 = u2h(xp.w);

  for (int it = 1; it < dmax; it += 4){
    const int c0 = min(it,     deg - 1);
    const int c1 = min(it + 1, deg - 1);
    const int c2 = min(it + 2, deg - 1);
    const int c3 = min(it + 3, deg - 1);
    const int s0 = csr_src[base + c0];
    const int s1 = csr_src[base + c1];
    const int s2 = csr_src[base + c2];
    const int s3 = csr_src[base + c3];
    const uint4 xA = *(const uint4*)(xl16 + (size_t)s0 * 128 + f8);
    const uint4 xB = *(const uint4*)(xl16 + (size_t)s1 * 128 + f8);
    const uint4 xC = *(const uint4*)(xl16 + (size_t)s2 * 128 + f8);
    const uint4 xD = *(const uint4*)(xl16 + (size_t)s3 * 128 + f8);
    float pA = part(xA), pB = part(xB), pC = part(xC), pD = part(xD);
    #pragma unroll
    for (int off = 1; off < 16; off <<= 1){
      pA += __shfl_xor(pA, off);
      pB += __shfl_xor(pB, off);
      pC += __shfl_xor(pC, off);
      pD += __shfl_xor(pD, off);
    }
    const bool vA = it < deg, vB = it + 1 < deg, vC = it + 2 < deg, vD = it + 3 < deg;
    float fA = vA ? pA : -3.0e38f;
    float fB = vB ? pB : -3.0e38f;
    float fC = vC ? pC : -3.0e38f;
    float fD = vD ? pD : -3.0e38f;
    Mrun = fmaxf(Mrun, fmaxf(fmaxf(fA, fB), fmaxf(fC, fD)));
    if (__any(Mrun > m + 8.f)){                   // rare, wave-uniform
      float sc = __expf(m - Mrun);
      s *= sc;
      _Float16 hs = (_Float16)sc;
      h2 scv = {hs, hs};
      A0 *= scv; A1 *= scv; A2 *= scv; A3 *= scv;
      m = Mrun;
    }
    float qA = vA ? __expf(pA - m) : 0.f;
    float qB = vB ? __expf(pB - m) : 0.f;
    float qC = vC ? __expf(pC - m) : 0.f;
    float qD = vD ? __expf(pD - m) : 0.f;
    s += (qA + qB) + (qC + qD);
    _Float16 ha = (_Float16)qA, hb = (_Float16)qB, hc = (_Float16)qC, hd = (_Float16)qD;
    h2 qa = {ha, ha}, qb = {hb, hb}, qc = {hc, hc}, qd = {hd, hd};
    A0 += u2h(xA.x) * qa; A1 += u2h(xA.y) * qa;
    A2 += u2h(xA.z) * qa; A3 += u2h(xA.w) * qa;
    A0 += u2h(xB.x) * qb; A1 += u2h(xB.y) * qb;
    A2 += u2h(xB.z) * qb; A3 += u2h(xB.w) * qb;
    A0 += u2h(xC.x) * qc; A1 += u2h(xC.y) * qc;
    A2 += u2h(xC.z) * qc; A3 += u2h(xC.w) * qc;
    A0 += u2h(xD.x) * qd; A1 += u2h(xD.y) * qd;
    A2 += u2h(xD.z) * qd; A3 += u2h(xD.w) * qd;
  }

  if (gid < n){
    const float inv = 1.0f / s;
    const float4 bA = *(const float4*)(bias + f8);
    const float4 bB = *(const float4*)(bias + f8 + 4);
    float o0 = fmaf((float)A0.x, inv, bA.x), o1 = fmaf((float)A0.y, inv, bA.y);
    float o2 = fmaf((float)A1.x, inv, bA.z), o3 = fmaf((float)A1.y, inv, bA.w);
    float o4 = fmaf((float)A2.x, inv, bB.x), o5 = fmaf((float)A2.y, inv, bB.y);
    float o6 = fmaf((float)A3.x, inv, bB.z), o7 = fmaf((float)A3.y, inv, bB.w);
    if (do_relu){
      o0 = fmaxf(o0, 0.f); o1 = fmaxf(o1, 0.f); o2 = fmaxf(o2, 0.f); o3 = fmaxf(o3, 0.f);
      o4 = fmaxf(o4, 0.f); o5 = fmaxf(o5, 0.f); o6 = fmaxf(o6, 0.f); o7 = fmaxf(o7, 0.f);
    }
    ushort4 wlo, whi;
    wlo.x = __builtin_bit_cast(unsigned short, (_Float16)o0);
    wlo.y = __builtin_bit_cast(unsigned short, (_Float16)o1);
    wlo.z = __builtin_bit_cast(unsigned short, (_Float16)o2);
    wlo.w = __builtin_bit_cast(unsigned short, (_Float16)o3);
    whi.x = __builtin_bit_cast(unsigned short, (_Float16)o4);
    whi.y = __builtin_bit_cast(unsigned short, (_Float16)o5);
    whi.z = __builtin_bit_cast(unsigned short, (_Float16)o6);
    whi.w = __builtin_bit_cast(unsigned short, (_Float16)o7);
    *(ushort4*)(out16 + (size_t)node * 128 + f8)     = wlo;
    *(ushort4*)(out16 + (size_t)node * 128 + f8 + 4) = whi;
  }
}

// ---------------- mean-pool + MLP head (f16 h input, vectorized) ----------
// threads 0..63 each own 2 feature-pairs (4 cols) via uint2 loads.
__global__ __launch_bounds__(128) void pool_mlp_kernel(
    const unsigned short* __restrict__ h, const int* __restrict__ batch, int n,
    const float* __restrict__ W4, const float* __restrict__ b4,
    const float* __restrict__ W5, const float* __restrict__ b5,
    const float* __restrict__ W6, const float* __restrict__ b6,
    float* __restrict__ out)
{
  int g = blockIdx.x;
  int t = threadIdx.x;
  __shared__ float gf[128];
  __shared__ float h1[128];
  __shared__ float h2s[64];
  int lo = dev_lower_bound(batch, n, g);
  int hi = dev_lower_bound(batch, n, g + 1);
  if (t < 32){
    // thread t sums cols 4t..4t+3 via uint2 (4 f16) loads
    float s0 = 0.f, s1 = 0.f, s2 = 0.f, s3 = 0.f;
    for (int i = lo; i < hi; ++i){
      uint2 v = *(const uint2*)(h + (size_t)i * 128 + t * 4);
      h2 p0 = u2h(v.x), p1 = u2h(v.y);
      s0 += (float)p0.x; s1 += (float)p0.y;
      s2 += (float)p1.x; s3 += (float)p1.y;
    }
    float inv = 1.0f / fmaxf((float)(hi - lo), 1.0f);
    gf[t * 4]     = s0 * inv;
    gf[t * 4 + 1] = s1 * inv;
    gf[t * 4 + 2] = s2 * inv;
    gf[t * 4 + 3] = s3 * inv;
  } else if (t < 64){
    int tt = t - 32;
    float s0 = 0.f, s1 = 0.f, s2 = 0.f, s3 = 0.f;
    for (int i = lo; i < hi; ++i){
      uint2 v = *(const uint2*)(h + (size_t)i * 128 + 64 + tt * 4);
      h2 p0 = u2h(v.x), p1 = u2h(v.y);
      s0 += (float)p0.x; s1 += (float)p0.y;
      s2 += (float)p1.x; s3 += (float)p1.y;
    }
    float inv = 1.0f / fmaxf((float)(hi - lo), 1.0f);
    gf[64 + tt * 4]     = s0 * inv;
    gf[64 + tt * 4 + 1] = s1 * inv;
    gf[64 + tt * 4 + 2] = s2 * inv;
    gf[64 + tt * 4 + 3] = s3 * inv;
  }
  __syncthreads();
  float a = b4[t];
  for (int k = 0; k < 128; ++k) a = fmaf(gf[k], W4[k * 128 + t], a);
  h1[t] = 1.0f / (1.0f + __expf(-a));
  __syncthreads();
  if (t < 64){
    float a5 = b5[t];
    for (int k = 0; k < 128; ++k) a5 = fmaf(h1[k], W5[k * 64 + t], a5);
    h2s[t] = 1.0f / (1.0f + __expf(-a5));
  }
  __syncthreads();
  if (t < 2){
    float a6 = b6[t];
    for (int k = 0; k < 64; ++k) a6 = fmaf(h2s[k], W6[k * 2 + t], a6);
    out[g * 2 + t] = a6;
  }
}

// ---------------- launcher ----------------
extern "C" void kernel_launch(void* const* d_in, const int* in_sizes, int n_in,
                              void* d_out, int out_size, void* d_ws, size_t ws_size,
                              hipStream_t stream)
{
  const float* x          = (const float*)d_in[0];
  const int*   edge_index = (const int*)d_in[1];
  const int*   batch      = (const int*)d_in[2];
  const int n  = in_sizes[0] / 128;            // 50000
  const int nE = in_sizes[1] / 2;              // 1600000
  const int* esrc = edge_index;
  const int* edst = edge_index + nE;
  const int n_graphs = out_size / 2;           // 512
  const int K = (n + BK_NODES - 1) >> BK_SHIFT;

  const float *Wl[3], *bl[3], *Wr[3], *br[3], *att[3], *bias[3];
  for (int l = 0; l < 3; ++l){
    Wl[l]   = (const float*)d_in[3 + 6 * l + 0];
    bl[l]   = (const float*)d_in[3 + 6 * l + 1];
    Wr[l]   = (const float*)d_in[3 + 6 * l + 2];
    br[l]   = (const float*)d_in[3 + 6 * l + 3];
    att[l]  = (const float*)d_in[3 + 6 * l + 4];
    bias[l] = (const float*)d_in[3 + 6 * l + 5];
  }
  const float* W4 = (const float*)d_in[21]; const float* b4 = (const float*)d_in[22];
  const float* W5 = (const float*)d_in[23]; const float* b5 = (const float*)d_in[24];
  const float* W6 = (const float*)d_in[25]; const float* b6 = (const float*)d_in[26];

  char* ws = (char*)d_ws;
  size_t off = 0;
  auto alloc = [&](size_t bytes) -> void* {
    void* p = ws + off;
    off = (off + bytes + 255) & ~(size_t)255;
    return p;
  };
  int*   row_off  = (int*)  alloc((size_t)(n + 1) * sizeof(int));
  int*   meta     = (int*)  alloc(1024 * sizeof(int));   // one memset covers all
  int*   bktCnt   = meta;               // 512
  int*   dbins    = meta + 512;         // 256
  int*   dres     = meta + 768;         // 256 (zero-based bin reservation)
  int*   order    = (int*)  alloc((size_t)n * sizeof(int));
  int*   csr_src  = (int*)  alloc((size_t)(nE + n) * sizeof(int) + 256);
  unsigned* ebuf  = (unsigned*)alloc((size_t)K * BK_CAP * sizeof(unsigned));
  unsigned short* xlb16 = (unsigned short*)alloc((size_t)n * 128 * sizeof(unsigned short));
  unsigned short* xrb16 = (unsigned short*)alloc((size_t)n * 128 * sizeof(unsigned short));
  unsigned short* Wt16  = (unsigned short*)alloc(6 * 16384 * sizeof(unsigned short));
  unsigned short* hC16  = (unsigned short*)alloc((size_t)n * 128 * sizeof(unsigned short));
  (void)ws_size; (void)n_in;

  hipMemsetAsync(meta, 0, 1024 * sizeof(int), stream);

  // ---- one-pass CSR build ----
  const int eblocks = (nE + 2048 - 1) / 2048;
  p3_prep_kernel<<<eblocks + 48, 256, 0, stream>>>(esrc, edst, bktCnt, ebuf, nE, K,
      Wl[0], Wr[0], Wl[1], Wr[1], Wl[2], Wr[2], Wt16);
  p4_build<<<K, 256, 0, stream>>>(ebuf, bktCnt, row_off, csr_src, dbins, n, nE);

  // ---- degree order (LPT), fused scan+scatter ----
  deg_scatter<<<(n + 255) / 256, 256, 0, stream>>>(row_off, dbins, dres, order, n);

  const int gemm_blocks = (n + 63) / 64;
  const int attn_blocks = (int)(((size_t)n * 16 + 255) / 256);

  // layer 1
  gemm_mfma_kernel<false><<<gemm_blocks, 256, 0, stream>>>(x, Wt16 + 0 * 32768,
                                                           bl[0], br[0], xlb16, xrb16, n);
  edge_attn_kernel<<<attn_blocks, 256, 0, stream>>>(xlb16, xrb16, row_off, csr_src, order,
                                                    att[0], bias[0], hC16, n, 1);
  // layer 2
  gemm_mfma_kernel<true><<<gemm_blocks, 256, 0, stream>>>(hC16, Wt16 + 1 * 32768,
                                                          bl[1], br[1], xlb16, xrb16, n);
  edge_attn_kernel<<<attn_blocks, 256, 0, stream>>>(xlb16, xrb16, row_off, csr_src, order,
                                                    att[1], bias[1], hC16, n, 1);
  // layer 3
  gemm_mfma_kernel<true><<<gemm_blocks, 256, 0, stream>>>(hC16, Wt16 + 2 * 32768,
                                                          bl[2], br[2], xlb16, xrb16, n);
  edge_attn_kernel<<<attn_blocks, 256, 0, stream>>>(xlb16, xrb16, row_off, csr_src, order,
                                                    att[2], bias[2], hC16, n, 0);

  pool_mlp_kernel<<<n_graphs, 128, 0, stream>>>(hC16, batch, n, W4, b4, W5, b5, W6, b6,
                                                (float*)d_out);
}

// Round 16
// 382.534 us; speedup vs baseline: 1.0832x; 1.0832x over previous
//
#include <hip/hip_runtime.h>
#include <math.h>

#define BK_SHIFT 7            // 128 nodes per bucket
#define BK_NODES 128
#define BK_CAP   4608         // slack bucket capacity: mean 4096 + 8 sigma

typedef _Float16 h2 __attribute__((ext_vector_type(2)));
typedef _Float16 f16x8 __attribute__((ext_vector_type(8)));
typedef float f32x4 __attribute__((ext_vector_type(4)));

__device__ __forceinline__ h2 u2h(unsigned u){ return __builtin_bit_cast(h2, u); }

__device__ __forceinline__ int dev_lower_bound(const int* __restrict__ a, int n, int v){
  int lo = 0, hi = n;
  while (lo < hi){ int mid = (lo + hi) >> 1; if (a[mid] < v) lo = mid + 1; else hi = mid; }
  return lo;
}

// ================= one-pass partition (+W-prep on blocks 0..47) =============
__global__ __launch_bounds__(256) void p3_prep_kernel(
    const int* __restrict__ esrc, const int* __restrict__ edst,
    int* __restrict__ bktCnt, unsigned* __restrict__ ebuf, int nE, int K,
    const float* __restrict__ W0, const float* __restrict__ W1,
    const float* __restrict__ W2, const float* __restrict__ W3,
    const float* __restrict__ W4m, const float* __restrict__ W5m,
    unsigned short* __restrict__ Wt16)
{
  __shared__ int cnt[512];
  __shared__ int base[512];
  if (blockIdx.x < 48){
    const float* Ws[6] = {W0, W1, W2, W3, W4m, W5m};
    const int mat = blockIdx.x >> 3;
    const int chunk = blockIdx.x & 7;
    const float* W = Ws[mat];
    unsigned short* o = Wt16 + mat * 16384;
    #pragma unroll
    for (int e = 0; e < 8; ++e){
      int i = chunk * 2048 + e * 256 + threadIdx.x;
      int k = i >> 7, col = i & 127;
      _Float16 h = (_Float16)W[i];
      o[col * 128 + k] = __builtin_bit_cast(unsigned short, h);
    }
    return;
  }
  const int bx = blockIdx.x - 48;
  const int t = threadIdx.x;
  for (int k = t; k < K; k += 256) cnt[k] = 0;
  __syncthreads();
  const int i0 = (bx * 256 + t) * 8;
  const int i1 = min(i0 + 8, nE);
  const int cl = (i0 < nE) ? (i1 - i0) : 0;
  int bkt[8];
  unsigned pk[8];
  for (int j = 0; j < cl; ++j){
    int sv = esrc[i0 + j];
    int dv = edst[i0 + j];
    bkt[j] = dv >> BK_SHIFT;
    pk[j] = ((unsigned)sv << BK_SHIFT) | (unsigned)(dv & (BK_NODES - 1));
    atomicAdd(&cnt[bkt[j]], 1);
  }
  __syncthreads();
  for (int k = t; k < K; k += 256){
    int c = cnt[k];
    base[k] = c ? atomicAdd(&bktCnt[k], c) : 0;   // global chunk reservation
  }
  __syncthreads();
  for (int k = t; k < K; k += 256) cnt[k] = 0;
  __syncthreads();
  for (int j = 0; j < cl; ++j){
    int r = atomicAdd(&cnt[bkt[j]], 1);
    ebuf[(size_t)bkt[j] * BK_CAP + base[bkt[j]] + r] = pk[j];
  }
}

// P4: per-bucket CSR build; e0 derived from actual bucket counts.
// Degree histogram (LPT-reversed bins) folded in. row_off[n] from block 0.
__global__ __launch_bounds__(256) void p4_build(const unsigned* __restrict__ ebuf,
    const int* __restrict__ bktCnt, int* __restrict__ row_off,
    int* __restrict__ csr_src, int* __restrict__ dbins, int n, int nE){
  const int b = blockIdx.x;
  const int node0 = b << BK_SHIFT;
  const int nNodes = min(BK_NODES, n - node0);
  const int tid = threadIdx.x;
  __shared__ int ldeg[BK_NODES];
  __shared__ int lcur[BK_NODES];
  __shared__ int sc[BK_NODES];
  __shared__ int dh[256];
  __shared__ int red[256];
  if (b == 0 && tid == 0) row_off[n] = nE + n;
  int partial = 0;
  for (int k = tid; k < b; k += 256) partial += bktCnt[k];
  red[tid] = partial;
  __syncthreads();
  for (int off = 128; off > 0; off >>= 1){
    if (tid < off) red[tid] += red[tid + off];
    __syncthreads();
  }
  const int e0 = red[0];
  const int ecnt = bktCnt[b];
  const unsigned* eb = ebuf + (size_t)b * BK_CAP;
  __syncthreads();
  if (tid < BK_NODES) ldeg[tid] = 0;
  dh[tid] = 0;
  __syncthreads();
  for (int i = tid; i < ecnt; i += 256)
    atomicAdd(&ldeg[eb[i] & (BK_NODES - 1)], 1);
  __syncthreads();
  if (tid < BK_NODES) sc[tid] = (tid < nNodes) ? (ldeg[tid] + 1) : 0;
  __syncthreads();
  for (int off = 1; off < BK_NODES; off <<= 1){
    int u = 0;
    if (tid < BK_NODES && tid >= off) u = sc[tid - off];
    __syncthreads();
    if (tid < BK_NODES) sc[tid] += u;
    __syncthreads();
  }
  if (tid < nNodes){
    const int csr0 = e0 + node0;
    int ro = csr0 + sc[tid] - (ldeg[tid] + 1);
    row_off[node0 + tid] = ro;
    lcur[tid] = ro;
    atomicAdd(&dh[255 - min(ldeg[tid] + 1, 255)], 1);   // LPT bins
  }
  __syncthreads();
  for (int i = tid; i < ecnt; i += 256){
    unsigned e = eb[i];
    int p = atomicAdd(&lcur[e & (BK_NODES - 1)], 1);
    csr_src[p] = (int)(e >> BK_SHIFT);
  }
  __syncthreads();
  if (tid < nNodes)
    csr_src[lcur[tid]] = node0 + tid;                   // self-loop at row end
  if (dh[tid]) atomicAdd(&dbins[tid], dh[tid]);
}

// ================= degree order (LPT): fused scan + scatter =================
__global__ __launch_bounds__(256) void deg_scatter(const int* __restrict__ row_off,
    const int* __restrict__ dbins, int* __restrict__ dres,
    int* __restrict__ order, int n){
  __shared__ int sh[256];
  __shared__ int cnt[256];
  __shared__ int base[256];
  const int t = threadIdx.x;
  const int v = dbins[t];
  sh[t] = v;
  cnt[t] = 0;
  __syncthreads();
  for (int off = 1; off < 256; off <<= 1){
    int u = (t >= off) ? sh[t - off] : 0;
    __syncthreads();
    sh[t] += u;
    __syncthreads();
  }
  const int gbase = sh[t] - v;       // exclusive global bin base
  __syncthreads();
  int i = blockIdx.x * 256 + t;
  int bin = 0, r = 0;
  if (i < n){
    int deg = row_off[i + 1] - row_off[i];
    bin = 255 - min(deg, 255);       // LPT: high degree first
    r = atomicAdd(&cnt[bin], 1);
  }
  __syncthreads();
  base[t] = cnt[t] ? (gbase + atomicAdd(&dres[t], cnt[t])) : 0;
  __syncthreads();
  if (i < n) order[base[bin] + r] = i;
}

// ---------------- MFMA GEMM: xl/xr = f16(X) @ {Wl,Wr} + b ------------------
template<bool F16IN>
__global__ __launch_bounds__(256) void gemm_mfma_kernel(
    const void* __restrict__ Xv,
    const unsigned short* __restrict__ WtL,   // [2][128col][128k] f16
    const float* __restrict__ bl, const float* __restrict__ br,
    unsigned short* __restrict__ xl16, unsigned short* __restrict__ xr16, int n)
{
  const int w   = threadIdx.x >> 6;
  const int l   = threadIdx.x & 63;
  const int l15 = l & 15;
  const int kq  = l >> 4;
  const int row = blockIdx.x * 64 + w * 16 + l15;
  const bool ok = row < n;
  const int rc = min(row, n - 1);

  f16x8 a[4];
  #pragma unroll
  for (int ks = 0; ks < 4; ++ks){
    if (F16IN){
      const unsigned short* src = (const unsigned short*)Xv + (size_t)rc * 128 + kq * 8 + ks * 32;
      a[ks] = ok ? *(const f16x8*)src : (f16x8){0,0,0,0,0,0,0,0};
    } else {
      const float* src = (const float*)Xv + (size_t)rc * 128 + kq * 8 + ks * 32;
      float4 f0 = ok ? *(const float4*)(src)     : make_float4(0.f,0.f,0.f,0.f);
      float4 f1 = ok ? *(const float4*)(src + 4) : make_float4(0.f,0.f,0.f,0.f);
      f16x8 v;
      v[0] = (_Float16)f0.x; v[1] = (_Float16)f0.y;
      v[2] = (_Float16)f0.z; v[3] = (_Float16)f0.w;
      v[4] = (_Float16)f1.x; v[5] = (_Float16)f1.y;
      v[6] = (_Float16)f1.z; v[7] = (_Float16)f1.w;
      a[ks] = v;
    }
  }

  const int rowblk = blockIdx.x * 64 + w * 16;
  #pragma unroll
  for (int mat = 0; mat < 2; ++mat){
    const unsigned short* Wt = WtL + mat * 16384;
    const float* bias = mat ? br : bl;
    unsigned short* out = mat ? xr16 : xl16;
    f32x4 acc[8];
    #pragma unroll
    for (int ct = 0; ct < 8; ++ct) acc[ct] = (f32x4){0.f, 0.f, 0.f, 0.f};
    #pragma unroll
    for (int ks = 0; ks < 4; ++ks){
      #pragma unroll
      for (int ct = 0; ct < 8; ++ct){
        f16x8 b = *(const f16x8*)(Wt + (size_t)(ct * 16 + l15) * 128 + ks * 32 + kq * 8);
        acc[ct] = __builtin_amdgcn_mfma_f32_16x16x32_f16(a[ks], b, acc[ct], 0, 0, 0);
      }
    }
    #pragma unroll
    for (int ct = 0; ct < 8; ++ct){
      const float bv = bias[ct * 16 + l15];
      #pragma unroll
      for (int rg = 0; rg < 4; ++rg){
        const int r = rowblk + kq * 4 + rg;
        if (r < n){
          _Float16 h = (_Float16)(acc[ct][rg] + bv);
          out[(size_t)r * 128 + ct * 16 + l15] = __builtin_bit_cast(unsigned short, h);
        }
      }
    }
  }
}

// ---------------- per-destination online-softmax attention ----------------
__global__ __launch_bounds__(256) void edge_attn_kernel(
    const unsigned short* __restrict__ xl16, const unsigned short* __restrict__ xr16,
    const int* __restrict__ row_off, const int* __restrict__ csr_src,
    const int* __restrict__ order,
    const float* __restrict__ att, const float* __restrict__ bias,
    unsigned short* __restrict__ out16, int n, int do_relu)
{
  const int gid = (blockIdx.x * blockDim.x + threadIdx.x) >> 4;
  const int node = order[min(gid, n - 1)];
  const int lane16 = threadIdx.x & 15;
  const int f8 = lane16 * 8;

  const uint4 xru = *(const uint4*)(xr16 + (size_t)node * 128 + f8);
  const h2 xr0 = u2h(xru.x), xr1 = u2h(xru.y), xr2 = u2h(xru.z), xr3 = u2h(xru.w);
  const float4 aA = *(const float4*)(att + f8);
  const float4 aB = *(const float4*)(att + f8 + 4);
  const h2 at0 = {(_Float16)aA.x, (_Float16)aA.y};
  const h2 at1 = {(_Float16)aA.z, (_Float16)aA.w};
  const h2 at2 = {(_Float16)aB.x, (_Float16)aB.y};
  const h2 at3 = {(_Float16)aB.z, (_Float16)aB.w};
  const h2 k02 = {(_Float16)0.2f, (_Float16)0.2f};

  const int base = row_off[node];
  const int deg  = row_off[node + 1] - base;
  int dmax = max(deg, __shfl_xor(deg, 16));
  dmax = max(dmax, __shfl_xor(dmax, 32));

  auto part = [&](uint4 xp) -> float {
    h2 u0 = u2h(xp.x) + xr0;
    h2 u1 = u2h(xp.y) + xr1;
    h2 u2 = u2h(xp.z) + xr2;
    h2 u3 = u2h(xp.w) + xr3;
    u0 = __builtin_elementwise_max(u0, u0 * k02);
    u1 = __builtin_elementwise_max(u1, u1 * k02);
    u2 = __builtin_elementwise_max(u2, u2 * k02);
    u3 = __builtin_elementwise_max(u3, u3 * k02);
    float ps = __builtin_amdgcn_fdot2(u0, at0, 0.f, false);
    ps = __builtin_amdgcn_fdot2(u1, at1, ps, false);
    ps = __builtin_amdgcn_fdot2(u2, at2, ps, false);
    ps = __builtin_amdgcn_fdot2(u3, at3, ps, false);
    return ps;
  };

  uint4 xp = *(const uint4*)(xl16 + (size_t)csr_src[base] * 128 + f8);
  float p = part(xp);
  p += __shfl_xor(p, 1); p += __shfl_xor(p, 2);
  p += __shfl_xor(p, 4); p += __shfl_xor(p, 8);
  float m = p, Mrun = p, s = 1.f;
  h2 A0 = u2h(xp.x), A1 = u2h(xp.y), A2 = u2h(xp.z), A3 = u2h(xp.w);

  for (int it = 1; it < dmax; it += 4){
    const int c0 = min(it,     deg - 1);
    const int c1 = min(it + 1, deg - 1);
    const int c2 = min(it + 2, deg - 1);
    const int c3 = min(it + 3, deg - 1);
    const int s0 = csr_src[base + c0];
    const int s1 = csr_src[base + c1];
    const int s2 = csr_src[base + c2];
    const int s3 = csr_src[base + c3];
    const uint4 xA = *(const uint4*)(xl16 + (size_t)s0 * 128 + f8);
    const uint4 xB = *(const uint4*)(xl16 + (size_t)s1 * 128 + f8);
    const uint4 xC = *(const uint4*)(xl16 + (size_t)s2 * 128 + f8);
    const uint4 xD = *(const uint4*)(xl16 + (size_t)s3 * 128 + f8);
    float pA = part(xA), pB = part(xB), pC = part(xC), pD = part(xD);
    #pragma unroll
    for (int off = 1; off < 16; off <<= 1){
      pA += __shfl_xor(pA, off);
      pB += __shfl_xor(pB, off);
      pC += __shfl_xor(pC, off);
      pD += __shfl_xor(pD, off);
    }
    const bool vA = it < deg, vB = it + 1 < deg, vC = it + 2 < deg, vD = it + 3 < deg;
    float fA = vA ? pA : -3.0e38f;
    float fB = vB ? pB : -3.0e38f;
    float fC = vC ? pC : -3.0e38f;
    float fD = vD ? pD : -3.0e38f;
    Mrun = fmaxf(Mrun, fmaxf(fmaxf(fA, fB), fmaxf(fC, fD)));
    if (__any(Mrun > m + 8.f)){                   // rare, wave-uniform
      float sc = __expf(m - Mrun);
      s *= sc;
      _Float16 hs = (_Float16)sc;
      h2 scv = {hs, hs};
      A0 *= scv; A1 *= scv; A2 *= scv; A3 *= scv;
      m = Mrun;
    }
    float qA = vA ? __expf(pA - m) : 0.f;
    float qB = vB ? __expf(pB - m) : 0.f;
    float qC = vC ? __expf(pC - m) : 0.f;
    float qD = vD ? __expf(pD - m) : 0.f;
    s += (qA + qB) + (qC + qD);
    _Float16 ha = (_Float16)qA, hb = (_Float16)qB, hc = (_Float16)qC, hd = (_Float16)qD;
    h2 qa = {ha, ha}, qb = {hb, hb}, qc = {hc, hc}, qd = {hd, hd};
    A0 += u2h(xA.x) * qa; A1 += u2h(xA.y) * qa;
    A2 += u2h(xA.z) * qa; A3 += u2h(xA.w) * qa;
    A0 += u2h(xB.x) * qb; A1 += u2h(xB.y) * qb;
    A2 += u2h(xB.z) * qb; A3 += u2h(xB.w) * qb;
    A0 += u2h(xC.x) * qc; A1 += u2h(xC.y) * qc;
    A2 += u2h(xC.z) * qc; A3 += u2h(xC.w) * qc;
    A0 += u2h(xD.x) * qd; A1 += u2h(xD.y) * qd;
    A2 += u2h(xD.z) * qd; A3 += u2h(xD.w) * qd;
  }

  if (gid < n){
    const float inv = 1.0f / s;
    const float4 bA = *(const float4*)(bias + f8);
    const float4 bB = *(const float4*)(bias + f8 + 4);
    float o0 = fmaf((float)A0.x, inv, bA.x), o1 = fmaf((float)A0.y, inv, bA.y);
    float o2 = fmaf((float)A1.x, inv, bA.z), o3 = fmaf((float)A1.y, inv, bA.w);
    float o4 = fmaf((float)A2.x, inv, bB.x), o5 = fmaf((float)A2.y, inv, bB.y);
    float o6 = fmaf((float)A3.x, inv, bB.z), o7 = fmaf((float)A3.y, inv, bB.w);
    if (do_relu){
      o0 = fmaxf(o0, 0.f); o1 = fmaxf(o1, 0.f); o2 = fmaxf(o2, 0.f); o3 = fmaxf(o3, 0.f);
      o4 = fmaxf(o4, 0.f); o5 = fmaxf(o5, 0.f); o6 = fmaxf(o6, 0.f); o7 = fmaxf(o7, 0.f);
    }
    ushort4 wlo, whi;
    wlo.x = __builtin_bit_cast(unsigned short, (_Float16)o0);
    wlo.y = __builtin_bit_cast(unsigned short, (_Float16)o1);
    wlo.z = __builtin_bit_cast(unsigned short, (_Float16)o2);
    wlo.w = __builtin_bit_cast(unsigned short, (_Float16)o3);
    whi.x = __builtin_bit_cast(unsigned short, (_Float16)o4);
    whi.y = __builtin_bit_cast(unsigned short, (_Float16)o5);
    whi.z = __builtin_bit_cast(unsigned short, (_Float16)o6);
    whi.w = __builtin_bit_cast(unsigned short, (_Float16)o7);
    *(ushort4*)(out16 + (size_t)node * 128 + f8)     = wlo;
    *(ushort4*)(out16 + (size_t)node * 128 + f8 + 4) = whi;
  }
}

// ---------------- mean-pool + MLP head (f16 h, uniform vectorized) --------
// All 128 threads active: thread t owns column-pair 2*(t&63) of rows
// lo+(t>>6), stepping by 2. Wave-partial sums merged via LDS.
__global__ __launch_bounds__(128) void pool_mlp_kernel(
    const unsigned short* __restrict__ h, const int* __restrict__ batch, int n,
    const float* __restrict__ W4, const float* __restrict__ b4,
    const float* __restrict__ W5, const float* __restrict__ b5,
    const float* __restrict__ W6, const float* __restrict__ b6,
    float* __restrict__ out)
{
  int g = blockIdx.x;
  int t = threadIdx.x;
  __shared__ float gfp[2][128];
  __shared__ float gf[128];
  __shared__ float h1[128];
  __shared__ float h2s[64];
  int lo = dev_lower_bound(batch, n, g);
  int hi = dev_lower_bound(batch, n, g + 1);
  const int half = t >> 6;            // wave id
  const int c2 = (t & 63) * 2;        // column pair
  float s0 = 0.f, s1 = 0.f;
  for (int i = lo + half; i < hi; i += 2){
    unsigned v = *(const unsigned*)(h + (size_t)i * 128 + c2);
    h2 p = u2h(v);
    s0 += (float)p.x; s1 += (float)p.y;
  }
  gfp[half][c2]     = s0;
  gfp[half][c2 + 1] = s1;
  __syncthreads();
  const float inv = 1.0f / fmaxf((float)(hi - lo), 1.0f);
  gf[t] = (gfp[0][t] + gfp[1][t]) * inv;
  __syncthreads();
  float a = b4[t];
  for (int k = 0; k < 128; ++k) a = fmaf(gf[k], W4[k * 128 + t], a);
  h1[t] = 1.0f / (1.0f + __expf(-a));
  __syncthreads();
  if (t < 64){
    float a5 = b5[t];
    for (int k = 0; k < 128; ++k) a5 = fmaf(h1[k], W5[k * 64 + t], a5);
    h2s[t] = 1.0f / (1.0f + __expf(-a5));
  }
  __syncthreads();
  if (t < 2){
    float a6 = b6[t];
    for (int k = 0; k < 64; ++k) a6 = fmaf(h2s[k], W6[k * 2 + t], a6);
    out[g * 2 + t] = a6;
  }
}

// ---------------- launcher ----------------
extern "C" void kernel_launch(void* const* d_in, const int* in_sizes, int n_in,
                              void* d_out, int out_size, void* d_ws, size_t ws_size,
                              hipStream_t stream)
{
  const float* x          = (const float*)d_in[0];
  const int*   edge_index = (const int*)d_in[1];
  const int*   batch      = (const int*)d_in[2];
  const int n  = in_sizes[0] / 128;            // 50000
  const int nE = in_sizes[1] / 2;              // 1600000
  const int* esrc = edge_index;
  const int* edst = edge_index + nE;
  const int n_graphs = out_size / 2;           // 512
  const int K = (n + BK_NODES - 1) >> BK_SHIFT;

  const float *Wl[3], *bl[3], *Wr[3], *br[3], *att[3], *bias[3];
  for (int l = 0; l < 3; ++l){
    Wl[l]   = (const float*)d_in[3 + 6 * l + 0];
    bl[l]   = (const float*)d_in[3 + 6 * l + 1];
    Wr[l]   = (const float*)d_in[3 + 6 * l + 2];
    br[l]   = (const float*)d_in[3 + 6 * l + 3];
    att[l]  = (const float*)d_in[3 + 6 * l + 4];
    bias[l] = (const float*)d_in[3 + 6 * l + 5];
  }
  const float* W4 = (const float*)d_in[21]; const float* b4 = (const float*)d_in[22];
  const float* W5 = (const float*)d_in[23]; const float* b5 = (const float*)d_in[24];
  const float* W6 = (const float*)d_in[25]; const float* b6 = (const float*)d_in[26];

  char* ws = (char*)d_ws;
  size_t off = 0;
  auto alloc = [&](size_t bytes) -> void* {
    void* p = ws + off;
    off = (off + bytes + 255) & ~(size_t)255;
    return p;
  };
  int*   row_off  = (int*)  alloc((size_t)(n + 1) * sizeof(int));
  int*   meta     = (int*)  alloc(1024 * sizeof(int));   // one memset covers all
  int*   bktCnt   = meta;               // 512
  int*   dbins    = meta + 512;         // 256
  int*   dres     = meta + 768;         // 256 (zero-based bin reservation)
  int*   order    = (int*)  alloc((size_t)n * sizeof(int));
  int*   csr_src  = (int*)  alloc((size_t)(nE + n) * sizeof(int) + 256);
  unsigned* ebuf  = (unsigned*)alloc((size_t)K * BK_CAP * sizeof(unsigned));
  unsigned short* xlb16 = (unsigned short*)alloc((size_t)n * 128 * sizeof(unsigned short));
  unsigned short* xrb16 = (unsigned short*)alloc((size_t)n * 128 * sizeof(unsigned short));
  unsigned short* Wt16  = (unsigned short*)alloc(6 * 16384 * sizeof(unsigned short));
  unsigned short* hC16  = (unsigned short*)alloc((size_t)n * 128 * sizeof(unsigned short));
  (void)ws_size; (void)n_in;

  hipMemsetAsync(meta, 0, 1024 * sizeof(int), stream);

  // ---- one-pass CSR build ----
  const int eblocks = (nE + 2048 - 1) / 2048;
  p3_prep_kernel<<<eblocks + 48, 256, 0, stream>>>(esrc, edst, bktCnt, ebuf, nE, K,
      Wl[0], Wr[0], Wl[1], Wr[1], Wl[2], Wr[2], Wt16);
  p4_build<<<K, 256, 0, stream>>>(ebuf, bktCnt, row_off, csr_src, dbins, n, nE);

  // ---- degree order (LPT), fused scan+scatter ----
  deg_scatter<<<(n + 255) / 256, 256, 0, stream>>>(row_off, dbins, dres, order, n);

  const int gemm_blocks = (n + 63) / 64;
  const int attn_blocks = (int)(((size_t)n * 16 + 255) / 256);

  // layer 1
  gemm_mfma_kernel<false><<<gemm_blocks, 256, 0, stream>>>(x, Wt16 + 0 * 32768,
                                                           bl[0], br[0], xlb16, xrb16, n);
  edge_attn_kernel<<<attn_blocks, 256, 0, stream>>>(xlb16, xrb16, row_off, csr_src, order,
                                                    att[0], bias[0], hC16, n, 1);
  // layer 2
  gemm_mfma_kernel<true><<<gemm_blocks, 256, 0, stream>>>(hC16, Wt16 + 1 * 32768,
                                                          bl[1], br[1], xlb16, xrb16, n);
  edge_attn_kernel<<<attn_blocks, 256, 0, stream>>>(xlb16, xrb16, row_off, csr_src, order,
                                                    att[1], bias[1], hC16, n, 1);
  // layer 3
  gemm_mfma_kernel<true><<<gemm_blocks, 256, 0, stream>>>(hC16, Wt16 + 2 * 32768,
                                                          bl[2], br[2], xlb16, xrb16, n);
  edge_attn_kernel<<<attn_blocks, 256, 0, stream>>>(xlb16, xrb16, row_off, csr_src, order,
                                                    att[2], bias[2], hC16, n, 0);

  pool_mlp_kernel<<<n_graphs, 128, 0, stream>>>(hC16, batch, n, W4, b4, W5, b5, W6, b6,
                                                (float*)d_out);
}